// Round 1
// baseline (168.347 us; speedup 1.0000x reference)
//
#include <hip/hip_runtime.h>

#define BB 2
#define NN 16384
#define CC 64
#define SS 4096
#define KK 32
#define R2 0.16f   // RADIUS^2

// spatial grid: cell = RADIUS, 32^3 cells covering [-6.4, 6.4] (clamped; the
// clamp is monotone so |cell(a)-cell(b)| <= |true diff| and the 3x3x3
// neighborhood remains a superset of the ball for ANY input magnitude)
#define GD   32
#define GC   (GD * GD * GD)       // 32768 cells per batch
#define CAP  1024                 // per-wave hit-list capacity (max expected ~350)
#define CAPL (CAP / 64)           // regs per lane for selection

typedef __bf16 bf16x8 __attribute__((ext_vector_type(8)));
typedef float  f32x4  __attribute__((ext_vector_type(4)));

#define MFMA(a, b, c) __builtin_amdgcn_mfma_f32_16x16x32_bf16((a), (b), (c), 0, 0, 0)

static __device__ __forceinline__ ushort f2bf(float f) {
    __bf16 h = (__bf16)f;
    return *(ushort*)&h;
}

static __device__ __forceinline__ int cellc(float x) {
    int i = (int)floorf(x * 2.5f + 16.0f);
    return i < 0 ? 0 : (i > GD - 1 ? GD - 1 : i);
}

// workspace section offsets (bytes), all 16B aligned
#define WS_PTS4   0          // pts4:    2*16384*16    =   524,288
#define WS_FEAT   524288     // feat_nc: 2*16384*64*2  = 4,194,304
#define WS_W1T    4718592    // 64*96*2   = 12,288
#define WS_W2T    4730880    // 64*64*2   =  8,192
#define WS_W3T    4739072    // 128*64*2  = 16,384
#define WS_SPTS   4755456    // sorted pts float4: 524,288
#define WS_SSID   5279744    // sorted orig idx:   131,072
#define WS_CNT    5410816    // cell counts/cursor: 2*32768*4 = 262,144
#define WS_OFF    5672960    // offsets: 2*32772*4 = 262,176  (end 5,935,136)

// prep index ranges
#define T_PTS   (BB * NN)                  // 32768
#define T_W1    (T_PTS + 64 * 96)          // 38912
#define T_W2    (T_W1 + 64 * 64)           // 43008
#define T_W3    (T_W2 + 128 * 64)          // 51200
#define T_NXYZ  (T_W3 + BB * SS * 3)       // 75776
#define T_SIDX  (T_NXYZ + BB * SS)         // 83968
#define T_ALL   (T_SIDX + BB * NN * 8)     // 346112 (feat threads, 8x split)

// ---------------------------------------------------------------------------
// prep: pts4=(x,y,z,|x|^2) + grid-cell count atomics; bf16 weight transposes;
// coalesced new_xyz copy; samp_idx; feat [B][C][N] fp32 -> [B][N][C] bf16 with
// 8 threads per point (4096 waves; the old 1-thread-per-point version was a
// 512-wave latency-bound tail). One launch.
// ---------------------------------------------------------------------------
__global__ __launch_bounds__(256) void prep_kernel(
        const float* __restrict__ xyz, const float* __restrict__ feat,
        const float* __restrict__ W1, const float* __restrict__ W2,
        const float* __restrict__ W3,
        float4* __restrict__ pts4, ushort* __restrict__ feat_nc,
        ushort* __restrict__ W1t, ushort* __restrict__ W2t,
        ushort* __restrict__ W3t,
        float* __restrict__ out_xyz, float* __restrict__ out_sidx,
        uint* __restrict__ counts) {
    const int t = blockIdx.x * 256 + threadIdx.x;
    if (t < T_PTS) {
        const float* p = xyz + (size_t)t * 3;
        const float x = p[0], y = p[1], z = p[2];
        pts4[t] = make_float4(x, y, z, x * x + y * y + z * z);
        const int cell = (((cellc(z) << 5) + cellc(y)) << 5) + cellc(x);
        atomicAdd(&counts[(t >> 14) * GC + cell], 1u);
    } else if (t < T_W1) {
        const int i = t - T_PTS;
        const int n = i / 96, k = i - n * 96;
        float v = 0.0f;
        if (k < 64) v = W1[(3 + k) * 64 + n];
        else if (k < 67) v = W1[(k - 64) * 64 + n];
        W1t[n * 96 + k] = f2bf(v);
    } else if (t < T_W2) {
        const int i = t - T_W1;
        const int n = i >> 6, k = i & 63;
        W2t[n * 64 + k] = f2bf(W2[k * 64 + n]);
    } else if (t < T_W3) {
        const int i = t - T_W2;
        const int n = i >> 6, k = i & 63;
        W3t[n * 64 + k] = f2bf(W3[k * 128 + n]);
    } else if (t < T_NXYZ) {
        const int i = t - T_W3;              // new_xyz = xyz[:, :SS] copy
        const int b = i / (SS * 3), j = i - b * (SS * 3);
        out_xyz[i] = xyz[(size_t)b * NN * 3 + j];
    } else if (t < T_SIDX) {
        const int i = t - T_NXYZ;
        out_sidx[i] = (float)(i & (SS - 1));
    } else if (t < T_ALL) {
        const int j = t - T_SIDX;            // 0 .. BB*NN*8-1
        const int nl = j >> 3, c8 = j & 7;   // nl: linear point, c8: channel oct
        const int b = nl >> 14, n = nl & (NN - 1);
        const float* fb = feat + (size_t)b * CC * NN + n;
        uint u[4];
        #pragma unroll
        for (int q = 0; q < 4; ++q) {
            const float f0 = fb[(size_t)(c8 * 8 + 2 * q) * NN];
            const float f1 = fb[(size_t)(c8 * 8 + 2 * q + 1) * NN];
            u[q] = (uint)f2bf(f0) | ((uint)f2bf(f1) << 16);
        }
        // consecutive j -> consecutive 16B: fully coalesced stores
        *(uint4*)(feat_nc + (size_t)nl * 64 + c8 * 8) = make_uint4(u[0], u[1], u[2], u[3]);
    }
}

// ---------------------------------------------------------------------------
// scan: exclusive prefix sum over 32768 cell counts per batch (1 block/batch).
// Writes offs[] (32769 entries used) and rewrites counts[] as scatter cursors.
// ---------------------------------------------------------------------------
__global__ __launch_bounds__(1024) void scan_kernel(uint* __restrict__ counts,
                                                    uint* __restrict__ offs) {
    __shared__ int lds[1024];
    const int b = blockIdx.x, t = threadIdx.x;
    uint* cnts = counts + (size_t)b * GC;
    uint* off  = offs + (size_t)b * 32772;
    int sum = 0;
    #pragma unroll
    for (int j = 0; j < 8; ++j) {
        const uint4 v = *((const uint4*)cnts + t * 8 + j);
        sum += (int)(v.x + v.y + v.z + v.w);
    }
    lds[t] = sum;
    __syncthreads();
    for (int d = 1; d < 1024; d <<= 1) {
        const int add = (t >= d) ? lds[t - d] : 0;
        __syncthreads();
        lds[t] += add;
        __syncthreads();
    }
    int run = lds[t] - sum;                  // exclusive prefix of this chunk
    #pragma unroll 4
    for (int j = 0; j < 32; ++j) {
        const int ci = t * 32 + j;
        const uint cv = cnts[ci];
        off[ci] = (uint)run;
        cnts[ci] = (uint)run;                // cursor start for scatter
        run += (int)cv;
    }
    if (t == 1023) off[GC] = (uint)run;      // == NN
}

// ---------------------------------------------------------------------------
// scatter: counting-sort points by cell (order within cell nondeterministic —
// harmless: the fused kernel selects by smallest original index).
// ---------------------------------------------------------------------------
__global__ __launch_bounds__(256) void scatter_kernel(
        const float4* __restrict__ pts4, uint* __restrict__ counts,
        float4* __restrict__ spts, int* __restrict__ ssid) {
    const int t = blockIdx.x * 256 + threadIdx.x;      // < BB*NN
    const int b = t >> 14;
    const float4 p = pts4[t];
    const int cell = (((cellc(p.z) << 5) + cellc(p.y)) << 5) + cellc(p.x);
    const uint pos = atomicAdd(&counts[(size_t)b * GC + cell], 1u);
    spts[(size_t)b * NN + pos] = p;
    ssid[(size_t)b * NN + pos] = t & (NN - 1);
}

// ---------------------------------------------------------------------------
// fused: one wave = one centroid. Grid ball-query: visit the 9 contiguous
// 3-cell runs of the 3x3x3 neighborhood (cells along x are contiguous in the
// sorted array), collect ALL in-radius hits (orig idx) into the wave's LDS
// scratch, then — since maxpool is order-invariant — keep the 32 smallest
// indices via a wave-parallel binary search on the index threshold.
// Sparse centroids (the old 64-iteration stragglers) now do ~9 empty-range
// checks. Then gather + 3-layer MLP + maxpool, unchanged.
// ---------------------------------------------------------------------------
__global__ __launch_bounds__(256, 2) void fused_kernel(
        const float4* __restrict__ pts4, const ushort* __restrict__ feat_nc,
        const float4* __restrict__ spts, const int* __restrict__ ssid,
        const uint* __restrict__ offs,
        const ushort* __restrict__ W1t, const ushort* __restrict__ W2t,
        const ushort* __restrict__ W3t,
        const float* __restrict__ b1, const float* __restrict__ b2,
        const float* __restrict__ b3, float* __restrict__ out_feat) {
    const int w = threadIdx.x >> 6, lane = threadIdx.x & 63;
    const int quad = lane >> 4, mrow = lane & 15;
    const int m = lane & 31, half = lane >> 5;

    __shared__ __align__(16) ushort ldsA[4][32 * 104];   // hits -> g -> h1 -> h2
    __shared__ float stage[128][5];                      // [ch][4 s + pad]
    ushort* gbuf = ldsA[w];
    int* hit = (int*)gbuf;                               // 4KB bq scratch (CAP ints)

    const int xcd = blockIdx.x & 7;
    const int slot = blockIdx.x >> 3;              // 0..255
    const int b = xcd >> 2;
    const int s0 = ((xcd & 3) * 256 + slot) * 4;   // block's 4-s tile
    const int s = s0 + w;

    const float4* pb = pts4 + (size_t)b * NN;
    const ushort* fbase = feat_nc + (size_t)b * NN * 64;
    const unsigned long long ltmask = (1ull << lane) - 1ull;

    // ================= ball query via grid =================
    {
        const float4 c = pb[s];
        const int cx = cellc(c.x), cy = cellc(c.y), cz = cellc(c.z);
        const int x0 = cx - 1 < 0 ? 0 : cx - 1;
        const int x1 = cx + 1 > GD - 1 ? GD - 1 : cx + 1;
        const uint* off = offs + (size_t)b * 32772;
        const float4* sp = spts + (size_t)b * NN;
        const int* sidp = ssid + (size_t)b * NN;
        int cnt = 0;
        #pragma unroll
        for (int e = 0; e < 9; ++e) {
            const int z = cz + e / 3 - 1, y = cy + e % 3 - 1;
            const bool ok = (z >= 0) && (z < GD) && (y >= 0) && (y < GD);
            const int cb = ((z << 5) + y) << 5;
            const int rs = ok ? (int)off[cb + x0] : 0;
            const int re = ok ? (int)off[cb + x1 + 1] : 0;
            for (int i0 = rs; i0 < re; i0 += 64) {
                const int iw = i0 + lane;
                const int ii = iw < re - 1 ? iw : re - 1;
                const bool act = iw < re;
                const float4 p = sp[ii];
                const int id = sidp[ii];
                const float d = c.w + p.w - 2.0f * (c.x * p.x + c.y * p.y + c.z * p.z);
                const bool h = act && (d < R2);
                const unsigned long long mk = __ballot(h);
                if (mk != 0ull) {
                    if (h) {
                        const int pp = cnt + __popcll(mk & ltmask);
                        if (pp < CAP) hit[pp] = id;
                    }
                    cnt += __popcll(mk);
                }
            }
        }
        // ---- keep the 32 smallest original indices (set-equivalent to the
        // reference "first nsample in index order"; maxpool ignores order) ----
        if (cnt > KK) {
            const int stored = cnt < CAP ? cnt : CAP;
            int v[CAPL];
            #pragma unroll
            for (int j = 0; j < CAPL; ++j) {
                const int q = j * 64 + lane;
                v[j] = (q < stored) ? hit[q] : 0x7fffffff;
            }
            int lo = 0, hi = NN - 1;
            while (lo < hi) {                    // wave-uniform, <=14 iters
                const int mid = (lo + hi) >> 1;
                int cle = 0;
                #pragma unroll
                for (int j = 0; j < CAPL; ++j) cle += (v[j] <= mid) ? 1 : 0;
                #pragma unroll
                for (int o = 1; o < 64; o <<= 1) cle += __shfl_xor(cle, o);
                if (cle >= KK) hi = mid; else lo = mid + 1;
            }
            int pos = 0;                         // exactly KK selected (ids unique)
            #pragma unroll
            for (int j = 0; j < CAPL; ++j) {
                const bool sel = v[j] <= lo;
                const unsigned long long mk = __ballot(sel);
                if (sel) hit[pos + __popcll(mk & ltmask)] = v[j];
                pos += __popcll(mk);
            }
        } else if (lane < KK) {
            const int vv = (cnt == 0) ? 0 : ((lane < cnt) ? hit[lane] : hit[0]);
            hit[lane] = vv;
        }
    }

    // ================= gather: sid (LDS) -> rows -> LDS =================
    {
        const int sid = hit[m];                  // wave-private, program order
        const ushort* src = fbase + (size_t)sid * 64 + half * 32;
        ushort* dst = gbuf + m * 104 + half * 32;
        uint4 rows[4];
        #pragma unroll
        for (int i = 0; i < 4; ++i) rows[i] = *(const uint4*)(src + i * 8);
        const float4 p = pb[sid];
        const float4 cc = pb[s];
        #pragma unroll
        for (int i = 0; i < 4; ++i) *(uint4*)(dst + i * 8) = rows[i];
        if (half == 0) {
            bf16x8 rel = {(__bf16)(p.x - cc.x), (__bf16)(p.y - cc.y),
                          (__bf16)(p.z - cc.z), (__bf16)0.f,
                          (__bf16)0.f, (__bf16)0.f, (__bf16)0.f, (__bf16)0.f};
            *(bf16x8*)(gbuf + m * 104 + 64) = rel;
            *(uint4*)(gbuf + m * 104 + 88) = make_uint4(0, 0, 0, 0);
        } else {
            *(uint4*)(gbuf + m * 104 + 72) = make_uint4(0, 0, 0, 0);
            *(uint4*)(gbuf + m * 104 + 80) = make_uint4(0, 0, 0, 0);
        }
    }

    // ================= layer 1: [32x96]x[96x64] =================
    {
        f32x4 acc[2][4];
        #pragma unroll
        for (int nt = 0; nt < 4; ++nt) {
            const float bv = b1[nt * 16 + mrow];
            acc[0][nt] = (f32x4){bv, bv, bv, bv};
            acc[1][nt] = acc[0][nt];
        }
        #pragma unroll
        for (int ks = 0; ks < 3; ++ks) {
            const bf16x8 a0 = *(const bf16x8*)(gbuf + mrow * 104 + ks * 32 + quad * 8);
            const bf16x8 a1 = *(const bf16x8*)(gbuf + (16 + mrow) * 104 + ks * 32 + quad * 8);
            #pragma unroll
            for (int nt = 0; nt < 4; ++nt) {
                const bf16x8 wf = *(const bf16x8*)(W1t + (nt * 16 + mrow) * 96 + ks * 32 + quad * 8);
                acc[0][nt] = MFMA(a0, wf, acc[0][nt]);
                acc[1][nt] = MFMA(a1, wf, acc[1][nt]);
            }
        }
        #pragma unroll
        for (int mt = 0; mt < 2; ++mt)
            #pragma unroll
            for (int nt = 0; nt < 4; ++nt)
                #pragma unroll
                for (int r = 0; r < 4; ++r)
                    gbuf[(mt * 16 + quad * 4 + r) * 104 + nt * 16 + mrow] =
                        f2bf(fmaxf(acc[mt][nt][r], 0.0f));
    }

    // ================= layer 2: [32x64]x[64x64] =================
    {
        f32x4 acc[2][4];
        #pragma unroll
        for (int nt = 0; nt < 4; ++nt) {
            const float bv = b2[nt * 16 + mrow];
            acc[0][nt] = (f32x4){bv, bv, bv, bv};
            acc[1][nt] = acc[0][nt];
        }
        #pragma unroll
        for (int ks = 0; ks < 2; ++ks) {
            const bf16x8 a0 = *(const bf16x8*)(gbuf + mrow * 104 + ks * 32 + quad * 8);
            const bf16x8 a1 = *(const bf16x8*)(gbuf + (16 + mrow) * 104 + ks * 32 + quad * 8);
            #pragma unroll
            for (int nt = 0; nt < 4; ++nt) {
                const bf16x8 wf = *(const bf16x8*)(W2t + (nt * 16 + mrow) * 64 + ks * 32 + quad * 8);
                acc[0][nt] = MFMA(a0, wf, acc[0][nt]);
                acc[1][nt] = MFMA(a1, wf, acc[1][nt]);
            }
        }
        #pragma unroll
        for (int mt = 0; mt < 2; ++mt)
            #pragma unroll
            for (int nt = 0; nt < 4; ++nt)
                #pragma unroll
                for (int r = 0; r < 4; ++r)
                    gbuf[(mt * 16 + quad * 4 + r) * 104 + nt * 16 + mrow] =
                        f2bf(fmaxf(acc[mt][nt][r], 0.0f));
    }

    // ============ layer 3: [32x64]x[64x128] two n-halves + maxpool ==========
    #pragma unroll
    for (int nh = 0; nh < 2; ++nh) {
        f32x4 acc[2][4];
        #pragma unroll
        for (int ntl = 0; ntl < 4; ++ntl) {
            const float bv = b3[(nh * 4 + ntl) * 16 + mrow];
            acc[0][ntl] = (f32x4){bv, bv, bv, bv};
            acc[1][ntl] = acc[0][ntl];
        }
        #pragma unroll
        for (int ks = 0; ks < 2; ++ks) {
            const bf16x8 a0 = *(const bf16x8*)(gbuf + mrow * 104 + ks * 32 + quad * 8);
            const bf16x8 a1 = *(const bf16x8*)(gbuf + (16 + mrow) * 104 + ks * 32 + quad * 8);
            #pragma unroll
            for (int ntl = 0; ntl < 4; ++ntl) {
                const bf16x8 wf = *(const bf16x8*)(
                    W3t + ((nh * 4 + ntl) * 16 + mrow) * 64 + ks * 32 + quad * 8);
                acc[0][ntl] = MFMA(a0, wf, acc[0][ntl]);
                acc[1][ntl] = MFMA(a1, wf, acc[1][ntl]);
            }
        }
        #pragma unroll
        for (int ntl = 0; ntl < 4; ++ntl) {
            const f32x4 v0 = acc[0][ntl], v1 = acc[1][ntl];
            float mx = fmaxf(fmaxf(v0[0], v0[1]), fmaxf(v0[2], v0[3]));
            mx = fmaxf(mx, fmaxf(fmaxf(v1[0], v1[1]), fmaxf(v1[2], v1[3])));
            mx = fmaxf(mx, __shfl_xor(mx, 16));
            mx = fmaxf(mx, __shfl_xor(mx, 32));
            mx = fmaxf(mx, 0.0f);
            if (quad == 0) stage[(nh * 4 + ntl) * 16 + mrow][w] = mx;
        }
    }
    __syncthreads();

    // ---- epilogue: 128 ch x 4 s, float2 per thread -------------------------
    {
        const int ch = threadIdx.x & 127;
        const int hf = threadIdx.x >> 7;           // 0/1
        float* dst = out_feat + ((size_t)b * 128 + ch) * SS + s0 + hf * 2;
        *(float2*)dst = make_float2(stage[ch][hf * 2], stage[ch][hf * 2 + 1]);
    }
}

// ---------------------------------------------------------------------------
extern "C" void kernel_launch(void* const* d_in, const int* in_sizes, int n_in,
                              void* d_out, int out_size, void* d_ws, size_t ws_size,
                              hipStream_t stream) {
    const float* xyz  = (const float*)d_in[0];
    const float* feat = (const float*)d_in[1];
    const float* W1   = (const float*)d_in[2];
    const float* b1   = (const float*)d_in[3];
    const float* W2   = (const float*)d_in[4];
    const float* b2   = (const float*)d_in[5];
    const float* W3   = (const float*)d_in[6];
    const float* b3   = (const float*)d_in[7];

    float* out      = (float*)d_out;
    float* out_xyz  = out;                               // [2,4096,3]
    float* out_feat = out + (size_t)BB * SS * 3;         // [2,128,4096]
    float* out_sidx = out_feat + (size_t)BB * 128 * SS;  // [2,4096]

    char* ws = (char*)d_ws;
    float4* pts4    = (float4*)(ws + WS_PTS4);
    ushort* feat_nc = (ushort*)(ws + WS_FEAT);
    ushort* W1t     = (ushort*)(ws + WS_W1T);
    ushort* W2t     = (ushort*)(ws + WS_W2T);
    ushort* W3t     = (ushort*)(ws + WS_W3T);
    float4* spts    = (float4*)(ws + WS_SPTS);
    int*    ssid    = (int*)(ws + WS_SSID);
    uint*   counts  = (uint*)(ws + WS_CNT);
    uint*   offs    = (uint*)(ws + WS_OFF);

    hipMemsetAsync(counts, 0, (size_t)BB * GC * 4, stream);
    prep_kernel<<<(T_ALL + 255) / 256, 256, 0, stream>>>(
        xyz, feat, W1, W2, W3, pts4, feat_nc, W1t, W2t, W3t, out_xyz, out_sidx,
        counts);
    scan_kernel<<<BB, 1024, 0, stream>>>(counts, offs);
    scatter_kernel<<<BB * NN / 256, 256, 0, stream>>>(pts4, counts, spts, ssid);
    fused_kernel<<<BB * SS / 4, 256, 0, stream>>>(pts4, feat_nc, spts, ssid, offs,
                                                  W1t, W2t, W3t, b1, b2, b3,
                                                  out_feat);
}